// Round 3
// baseline (163.948 us; speedup 1.0000x reference)
//
#include <hip/hip_runtime.h>
#include <hip/hip_bf16.h>
#include <math.h>

// spatialAttention: B=512, P=128, D=64, domain 12x12, W [64,128], out [512,128,64] f32
#define NB 512
#define NP 128
#define ND 64
#define EPSF 1e-5f
// bf16-element row stride for MFMA-read LDS arrays: 136 elems = 272 B.
// 272 % 16 == 0 -> every short8 frag access is 16B-aligned; frag-read bank
// aliasing is 2-way (free per m136).
#define SW 136

typedef __attribute__((ext_vector_type(8))) short short8;   // 8 bf16 = 4 VGPRs
typedef __attribute__((ext_vector_type(4))) float f32x4;    // MFMA accumulator

__device__ __forceinline__ short f2bf(float x) {
    __hip_bfloat16 h = __float2bfloat16(x);
    return *reinterpret_cast<short*>(&h);
}

// ============================================================================
// Kernel 1: masked-softmax weights, one wave per (b,p) row. Pure streaming.
// 16384 blocks x 256 thr; ~1KB LDS; high occupancy -> HBM-bound.
// ============================================================================
__global__ __launch_bounds__(256, 4) void weights_kernel(
    const float* __restrict__ dist,     // [B,P,P]
    const float* __restrict__ bear,     // [B,P,P]
    const float* __restrict__ head,     // [B,P,P]
    const float* __restrict__ smask,    // [B,P]
    const float* __restrict__ domain,   // [12,12]
    short* __restrict__ wout)           // [B,P,P] bf16
{
    __shared__ float s_dom[144];
    __shared__ float s_mask[NP];

    const int blk  = blockIdx.x;        // 32 blocks per batch, 4 rows per block
    const int b    = blk >> 5;
    const int p0   = (blk & 31) * 4;
    const int tid  = threadIdx.x;
    const int lane = tid & 63;
    const int wave = tid >> 6;

    if (tid < 144) s_dom[tid] = domain[tid];
    if (tid < NP)  s_mask[tid] = smask[b * NP + tid];
    __syncthreads();

    const int p = p0 + wave;
    const size_t ro = ((size_t)b * NP + p) * NP;

    float dq0 = dist[ro + lane], dq1 = dist[ro + lane + 64];
    float bq0 = bear[ro + lane], bq1 = bear[ro + lane + 64];
    float hq0 = head[ro + lane], hq1 = head[ro + lane + 64];
    const float mp  = s_mask[p];
    const float mq0 = s_mask[lane], mq1 = s_mask[lane + 64];

    // true IEEE division by 30.0f: matches numpy floor(x/30) at bin edges
    int i1 = (int)floorf(hq0 / 30.0f); i1 = i1 < 0 ? 0 : (i1 > 11 ? 11 : i1);
    int i2 = (int)floorf(bq0 / 30.0f); i2 = i2 < 0 ? 0 : (i2 > 11 ? 11 : i2);
    float wv0 = s_dom[i1 * 12 + i2] - dq0;
    bool on0 = (wv0 > 0.0f) && (mp != 0.0f) && (mq0 != 0.0f) && (lane != p);
    float e0 = on0 ? (expf(wv0) + EPSF) : EPSF;

    int k1 = (int)floorf(hq1 / 30.0f); k1 = k1 < 0 ? 0 : (k1 > 11 ? 11 : k1);
    int k2 = (int)floorf(bq1 / 30.0f); k2 = k2 < 0 ? 0 : (k2 > 11 ? 11 : k2);
    float wv1 = s_dom[k1 * 12 + k2] - dq1;
    bool on1 = (wv1 > 0.0f) && (mp != 0.0f) && (mq1 != 0.0f) && ((lane + 64) != p);
    float e1 = on1 ? (expf(wv1) + EPSF) : EPSF;

    float ssum = e0 + e1;
    #pragma unroll
    for (int off = 32; off > 0; off >>= 1)
        ssum += __shfl_xor(ssum, off, 64);
    float inv = 1.0f / (ssum + EPSF);

    wout[ro + lane]      = f2bf(e0 * inv);
    wout[ro + lane + 64] = f2bf(e1 * inv);
}

// ============================================================================
// Kernel 2: wh = w @ h; out = tanh([wh|h] @ W^T + b). MFMA, 2 blocks/batch
// (64 rows each), 52KB LDS -> 3 blocks/CU, 1024 blocks.
// ============================================================================
__global__ __launch_bounds__(256, 3) void fuse_kernel(
    const short* __restrict__ win,      // [B,P,P] bf16 weights
    const float* __restrict__ hidden,   // [B,P,D]
    const float* __restrict__ W,        // [D, 2D] row-major
    const float* __restrict__ bias,     // [D]
    float* __restrict__ out)            // [B,P,D]
{
    __shared__ __align__(16) short s_w[64 * SW];   // 17408 B: weights, then [wh|h]
    __shared__ __align__(16) short s_hT[ND * SW];  // 17408 B: s_hT[d][q] = h[q][d]
    __shared__ __align__(16) short s_Wm[ND * SW];  // 17408 B: s_Wm[d][k] = W[d][k]

    const int blk  = blockIdx.x;        // 2 blocks per batch
    const int b    = blk >> 1;
    const int half = blk & 1;           // rows [half*64, half*64+64)
    const int tid  = threadIdx.x;
    const int lane = tid & 63;
    const int wave = tid >> 6;
    const int quad = lane >> 4;
    const int l16  = lane & 15;

    // ---- stage this half's 64 weight rows (bf16, 16B chunks, coalesced) ----
    {
        const short8* wsrc = (const short8*)(win + ((size_t)b * NP + half * 64) * NP);
        #pragma unroll
        for (int i = 0; i < 4; ++i) {
            int idx = tid + i * 256;        // 1024 chunks of 8 bf16
            int row = idx >> 4;             // 16 chunks per 128-elem row
            int col = (idx & 15) * 8;
            *(short8*)&s_w[row * SW + col] = wsrc[idx];
        }
    }
    // ---- stage hidden^T as bf16 (all 128 q rows; transpose during store) ----
    {
        const float4* hsrc = (const float4*)(hidden + (size_t)b * NP * ND);
        #pragma unroll
        for (int i = 0; i < 8; ++i) {
            int idx = tid + i * 256;        // 2048 float4
            float4 v = hsrc[idx];
            int q = idx >> 4;
            int d = (idx & 15) * 4;
            s_hT[(d + 0) * SW + q] = f2bf(v.x);
            s_hT[(d + 1) * SW + q] = f2bf(v.y);
            s_hT[(d + 2) * SW + q] = f2bf(v.z);
            s_hT[(d + 3) * SW + q] = f2bf(v.w);
        }
    }
    // ---- stage W as bf16 row-major [d][k] ----
    {
        #pragma unroll
        for (int i = 0; i < 8; ++i) {
            int idx = tid + i * 256;        // 2048 float4
            float4 v = ((const float4*)W)[idx];
            int d = idx >> 5;
            int k = (idx & 31) * 4;
            short4 s4;
            s4.x = f2bf(v.x); s4.y = f2bf(v.y); s4.z = f2bf(v.z); s4.w = f2bf(v.w);
            *(short4*)&s_Wm[d * SW + k] = s4;
        }
    }
    __syncthreads();

    const int R0 = wave * 16;               // local row base (of 64)
    const int G0 = half * 64 + R0;          // global row base (of 128)

    // ---- phase 2: wh = w @ h, 16x64 tile per wave via MFMA (K=128) ----
    f32x4 acc[4];
    #pragma unroll
    for (int tj = 0; tj < 4; ++tj) acc[tj] = (f32x4){0.f, 0.f, 0.f, 0.f};

    #pragma unroll
    for (int kb = 0; kb < 4; ++kb) {
        const int ko = kb * 32 + quad * 8;
        short8 a = *(const short8*)&s_w[(R0 + l16) * SW + ko];
        #pragma unroll
        for (int tj = 0; tj < 4; ++tj) {
            short8 bf = *(const short8*)&s_hT[(tj * 16 + l16) * SW + ko];
            acc[tj] = __builtin_amdgcn_mfma_f32_16x16x32_bf16(a, bf, acc[tj], 0, 0, 0);
        }
    }

    // ---- build fused rows [wh | h] in s_w (wave-local; DS is in-order) ----
    // C/D layout: row = quad*4 + reg, col = l16
    #pragma unroll
    for (int tj = 0; tj < 4; ++tj)
        #pragma unroll
        for (int r = 0; r < 4; ++r) {
            int row = R0 + quad * 4 + r;
            s_w[row * SW + tj * 16 + l16] = f2bf(acc[tj][r]);
        }
    {
        const float* hb = hidden + (size_t)b * NP * ND;
        #pragma unroll 4
        for (int i = 0; i < 16; ++i) {      // L2-warm coalesced re-read of own rows
            float hv = hb[(size_t)(G0 + i) * ND + lane];
            s_w[(R0 + i) * SW + 64 + lane] = f2bf(hv);
        }
    }

    // ---- phase 3: out = tanh(fused @ W^T + b) via MFMA (K=128) ----
    f32x4 acc2[4];
    #pragma unroll
    for (int tj = 0; tj < 4; ++tj) acc2[tj] = (f32x4){0.f, 0.f, 0.f, 0.f};

    #pragma unroll
    for (int kb = 0; kb < 4; ++kb) {
        const int ko = kb * 32 + quad * 8;
        short8 a = *(const short8*)&s_w[(R0 + l16) * SW + ko];
        #pragma unroll
        for (int tj = 0; tj < 4; ++tj) {
            short8 bf = *(const short8*)&s_Wm[(tj * 16 + l16) * SW + ko];
            acc2[tj] = __builtin_amdgcn_mfma_f32_16x16x32_bf16(a, bf, acc2[tj], 0, 0, 0);
        }
    }

    float bvals[4];
    #pragma unroll
    for (int tj = 0; tj < 4; ++tj) bvals[tj] = bias[tj * 16 + l16];

    float* ob = out + (size_t)b * NP * ND;
    #pragma unroll
    for (int tj = 0; tj < 4; ++tj)
        #pragma unroll
        for (int r = 0; r < 4; ++r) {
            int row = G0 + quad * 4 + r;
            ob[(size_t)row * ND + tj * 16 + l16] = tanhf(acc2[tj][r] + bvals[tj]);
        }
}

// ============================================================================
// Fallback: round-2 single kernel (used only if ws_size is too small).
// ============================================================================
__global__ __launch_bounds__(256, 2) void spatial_attn_single(
    const float* __restrict__ hidden, const float* __restrict__ dist,
    const float* __restrict__ bear, const float* __restrict__ head,
    const float* __restrict__ smask, const float* __restrict__ domain,
    const float* __restrict__ W, const float* __restrict__ bias,
    float* __restrict__ out)
{
    __shared__ __align__(16) short s_w[NP * SW];
    __shared__ __align__(16) short s_hT[ND * SW];
    __shared__ __align__(16) short s_Wm[ND * SW];
    __shared__ float s_dom[144];
    __shared__ float s_mask[NP];

    const int b = blockIdx.x, tid = threadIdx.x;
    const int lane = tid & 63, wave = tid >> 6, quad = lane >> 4, l16 = lane & 15;

    {
        const float4* hsrc = (const float4*)(hidden + (size_t)b * NP * ND);
        #pragma unroll
        for (int i = 0; i < 8; ++i) {
            int idx = tid + i * 256;
            float4 v = hsrc[idx];
            int q = idx >> 4, d = (idx & 15) * 4;
            s_hT[(d + 0) * SW + q] = f2bf(v.x);
            s_hT[(d + 1) * SW + q] = f2bf(v.y);
            s_hT[(d + 2) * SW + q] = f2bf(v.z);
            s_hT[(d + 3) * SW + q] = f2bf(v.w);
        }
        #pragma unroll
        for (int i = 0; i < 8; ++i) {
            int idx = tid + i * 256;
            float4 v = ((const float4*)W)[idx];
            int d = idx >> 5, k = (idx & 31) * 4;
            short4 s4;
            s4.x = f2bf(v.x); s4.y = f2bf(v.y); s4.z = f2bf(v.z); s4.w = f2bf(v.w);
            *(short4*)&s_Wm[d * SW + k] = s4;
        }
    }
    if (tid < 144) s_dom[tid] = domain[tid];
    if (tid < NP)  s_mask[tid] = smask[b * NP + tid];
    __syncthreads();

    const int R0 = wave * 32;
    const size_t rowbase = (size_t)b * NP * NP;
    const float mq0 = s_mask[lane], mq1 = s_mask[lane + 64];

    for (int j = 0; j < 8; ++j) {
        #pragma unroll
        for (int r = 0; r < 4; ++r) {
            const int p = R0 + j * 4 + r;
            const size_t ro = rowbase + (size_t)p * NP;
            float dq0 = dist[ro + lane], dq1 = dist[ro + lane + 64];
            float bq0 = bear[ro + lane], bq1 = bear[ro + lane + 64];
            float hq0 = head[ro + lane], hq1 = head[ro + lane + 64];
            const float mp = s_mask[p];
            int i1 = (int)floorf(hq0 / 30.0f); i1 = i1 < 0 ? 0 : (i1 > 11 ? 11 : i1);
            int i2 = (int)floorf(bq0 / 30.0f); i2 = i2 < 0 ? 0 : (i2 > 11 ? 11 : i2);
            float wv0 = s_dom[i1 * 12 + i2] - dq0;
            bool on0 = (wv0 > 0.0f) && (mp != 0.0f) && (mq0 != 0.0f) && (lane != p);
            float e0 = on0 ? (expf(wv0) + EPSF) : EPSF;
            int k1 = (int)floorf(hq1 / 30.0f); k1 = k1 < 0 ? 0 : (k1 > 11 ? 11 : k1);
            int k2 = (int)floorf(bq1 / 30.0f); k2 = k2 < 0 ? 0 : (k2 > 11 ? 11 : k2);
            float wv1 = s_dom[k1 * 12 + k2] - dq1;
            bool on1 = (wv1 > 0.0f) && (mp != 0.0f) && (mq1 != 0.0f) && ((lane + 64) != p);
            float e1 = on1 ? (expf(wv1) + EPSF) : EPSF;
            float ssum = e0 + e1;
            #pragma unroll
            for (int off = 32; off > 0; off >>= 1)
                ssum += __shfl_xor(ssum, off, 64);
            float inv = 1.0f / (ssum + EPSF);
            s_w[p * SW + lane]      = f2bf(e0 * inv);
            s_w[p * SW + lane + 64] = f2bf(e1 * inv);
        }
    }

    f32x4 acc[2][4];
    #pragma unroll
    for (int ti = 0; ti < 2; ++ti)
        #pragma unroll
        for (int tj = 0; tj < 4; ++tj) acc[ti][tj] = (f32x4){0.f, 0.f, 0.f, 0.f};
    #pragma unroll
    for (int kb = 0; kb < 4; ++kb) {
        const int ko = kb * 32 + quad * 8;
        short8 a0 = *(const short8*)&s_w[(R0 + l16) * SW + ko];
        short8 a1 = *(const short8*)&s_w[(R0 + 16 + l16) * SW + ko];
        #pragma unroll
        for (int tj = 0; tj < 4; ++tj) {
            short8 bf = *(const short8*)&s_hT[(tj * 16 + l16) * SW + ko];
            acc[0][tj] = __builtin_amdgcn_mfma_f32_16x16x32_bf16(a0, bf, acc[0][tj], 0, 0, 0);
            acc[1][tj] = __builtin_amdgcn_mfma_f32_16x16x32_bf16(a1, bf, acc[1][tj], 0, 0, 0);
        }
    }
    #pragma unroll
    for (int ti = 0; ti < 2; ++ti)
        #pragma unroll
        for (int tj = 0; tj < 4; ++tj)
            #pragma unroll
            for (int r = 0; r < 4; ++r) {
                int row = R0 + ti * 16 + quad * 4 + r;
                s_w[row * SW + tj * 16 + l16] = f2bf(acc[ti][tj][r]);
            }
    {
        const float* hb = hidden + (size_t)b * NP * ND;
        #pragma unroll 4
        for (int i = 0; i < 32; ++i) {
            float hv = hb[(size_t)(R0 + i) * ND + lane];
            s_w[(R0 + i) * SW + 64 + lane] = f2bf(hv);
        }
    }
    f32x4 acc2[2][4];
    #pragma unroll
    for (int ti = 0; ti < 2; ++ti)
        #pragma unroll
        for (int tj = 0; tj < 4; ++tj) acc2[ti][tj] = (f32x4){0.f, 0.f, 0.f, 0.f};
    #pragma unroll
    for (int kb = 0; kb < 4; ++kb) {
        const int ko = kb * 32 + quad * 8;
        short8 a0 = *(const short8*)&s_w[(R0 + l16) * SW + ko];
        short8 a1 = *(const short8*)&s_w[(R0 + 16 + l16) * SW + ko];
        #pragma unroll
        for (int tj = 0; tj < 4; ++tj) {
            short8 bf = *(const short8*)&s_Wm[(tj * 16 + l16) * SW + ko];
            acc2[0][tj] = __builtin_amdgcn_mfma_f32_16x16x32_bf16(a0, bf, acc2[0][tj], 0, 0, 0);
            acc2[1][tj] = __builtin_amdgcn_mfma_f32_16x16x32_bf16(a1, bf, acc2[1][tj], 0, 0, 0);
        }
    }
    float bvals[4];
    #pragma unroll
    for (int tj = 0; tj < 4; ++tj) bvals[tj] = bias[tj * 16 + l16];
    float* ob = out + (size_t)b * NP * ND;
    #pragma unroll
    for (int ti = 0; ti < 2; ++ti)
        #pragma unroll
        for (int tj = 0; tj < 4; ++tj)
            #pragma unroll
            for (int r = 0; r < 4; ++r) {
                int row = R0 + ti * 16 + quad * 4 + r;
                ob[(size_t)row * ND + tj * 16 + l16] = tanhf(acc2[ti][tj][r] + bvals[tj]);
            }
}

extern "C" void kernel_launch(void* const* d_in, const int* in_sizes, int n_in,
                              void* d_out, int out_size, void* d_ws, size_t ws_size,
                              hipStream_t stream) {
    const float* hidden = (const float*)d_in[0];
    const float* dist   = (const float*)d_in[1];
    const float* bear   = (const float*)d_in[2];
    const float* head   = (const float*)d_in[3];
    const float* smask  = (const float*)d_in[4];
    const float* domain = (const float*)d_in[5];
    const float* W      = (const float*)d_in[6];
    const float* bias   = (const float*)d_in[7];
    float* out = (float*)d_out;

    const size_t need = (size_t)NB * NP * NP * sizeof(short);  // 16.8 MB bf16 weights
    if (ws_size >= need) {
        short* wbuf = (short*)d_ws;
        weights_kernel<<<dim3(NB * 32), dim3(256), 0, stream>>>(
            dist, bear, head, smask, domain, wbuf);
        fuse_kernel<<<dim3(NB * 2), dim3(256), 0, stream>>>(
            wbuf, hidden, W, bias, out);
    } else {
        spatial_attn_single<<<dim3(NB), dim3(256), 0, stream>>>(
            hidden, dist, bear, head, smask, domain, W, bias, out);
    }
}

// Round 4
// 157.218 us; speedup vs baseline: 1.0428x; 1.0428x over previous
//
#include <hip/hip_runtime.h>
#include <hip/hip_bf16.h>
#include <math.h>

// spatialAttention: B=512, P=128, D=64, domain 12x12, W [64,128], out [512,128,64] f32
#define NB 512
#define NP 128
#define ND 64
#define EPSF 1e-5f
// bf16-element row stride for MFMA-read LDS arrays: 136 elems = 272 B.
// 272 % 16 == 0 -> every short8 frag access is 16B-aligned; frag-read bank
// aliasing is 2-way (free per m136).
#define SW 136

typedef __attribute__((ext_vector_type(8))) short short8;   // 8 bf16 = 4 VGPRs
typedef __attribute__((ext_vector_type(4))) float f32x4;    // MFMA accumulator

__device__ __forceinline__ short f2bf(float x) {
    __hip_bfloat16 h = __float2bfloat16(x);
    return *reinterpret_cast<short*>(&h);
}

// One block per batch, 512 threads = 8 waves; wave w owns rows [16w, 16w+16).
// 71 KB LDS -> 2 blocks/CU -> 16 waves/CU (4/SIMD). Single __syncthreads.
//   phase 1: UNNORMALIZED E = exp(w)+eps (masked) -> bf16 LDS. No cross-lane
//            ops: softmax denominators come later from MFMA row sums, since
//            (E/s)@h = diag(1/s)(E@h).
//   phase 2: E@h via MFMA (K=128) + ones-MFMA row sums; scale by 1/(s+eps)
//            while converting C->A layout in LDS; append h -> fused [wh|h].
//   phase 3: out = tanh(fused @ W^T + b) via MFMA (K=128).
__global__ __launch_bounds__(512, 4) void spatial_attn_kernel(
    const float* __restrict__ hidden,   // [B,P,D]
    const float* __restrict__ dist,     // [B,P,P]
    const float* __restrict__ bear,     // [B,P,P]
    const float* __restrict__ head,     // [B,P,P]
    const float* __restrict__ smask,    // [B,P]
    const float* __restrict__ domain,   // [12,12]
    const float* __restrict__ W,        // [D, 2D] row-major
    const float* __restrict__ bias,     // [D]
    float* __restrict__ out)            // [B,P,D]
{
    __shared__ __align__(16) short s_w[NP * SW];   // 34816 B: E, then [wh|h]
    __shared__ __align__(16) short s_hT[ND * SW];  // 17408 B: s_hT[d][q] = h[q][d]
    __shared__ __align__(16) short s_Wm[ND * SW];  // 17408 B: s_Wm[d][k] = W[d][k]
    __shared__ float s_dom[144];
    __shared__ float s_mask[NP];

    const int b    = blockIdx.x;
    const int tid  = threadIdx.x;
    const int lane = tid & 63;
    const int wave = tid >> 6;          // 0..7
    const int quad = lane >> 4;
    const int l16  = lane & 15;

    // ---- stage hidden^T as bf16 (transpose during store) ----
    {
        const float4* hsrc = (const float4*)(hidden + (size_t)b * NP * ND);
        #pragma unroll
        for (int i = 0; i < 4; ++i) {
            int idx = tid + i * 512;          // 2048 float4
            float4 v = hsrc[idx];
            int q = idx >> 4;                 // elem/64
            int d = (idx & 15) * 4;           // elem%64, 4-aligned
            s_hT[(d + 0) * SW + q] = f2bf(v.x);
            s_hT[(d + 1) * SW + q] = f2bf(v.y);
            s_hT[(d + 2) * SW + q] = f2bf(v.z);
            s_hT[(d + 3) * SW + q] = f2bf(v.w);
        }
    }
    // ---- stage W as bf16 row-major [d][k] ----
    {
        #pragma unroll
        for (int i = 0; i < 4; ++i) {
            int idx = tid + i * 512;          // 2048 float4
            float4 v = ((const float4*)W)[idx];
            int d = idx >> 5;                 // elem/128
            int k = (idx & 31) * 4;           // elem%128, 4-aligned
            short4 s4;
            s4.x = f2bf(v.x); s4.y = f2bf(v.y); s4.z = f2bf(v.z); s4.w = f2bf(v.w);
            *(short4*)&s_Wm[d * SW + k] = s4;
        }
    }
    if (tid < 144) s_dom[tid] = domain[tid];
    if (tid < NP)  s_mask[tid] = smask[b * NP + tid];
    __syncthreads();   // the only block-wide barrier

    const int R0 = wave * 16;
    const size_t rowbase = (size_t)b * NP * NP;
    const float mq0 = s_mask[lane], mq1 = s_mask[lane + 64];

    // ---- phase 1: unnormalized masked exp, 16 own rows, no cross-lane ops ----
    for (int j0 = 0; j0 < 16; j0 += 4) {
        #pragma unroll
        for (int r = 0; r < 4; ++r) {
            const int p = R0 + j0 + r;
            const size_t ro = rowbase + (size_t)p * NP;
            float dq0 = dist[ro + lane], dq1 = dist[ro + lane + 64];
            float bq0 = bear[ro + lane], bq1 = bear[ro + lane + 64];
            float hq0 = head[ro + lane], hq1 = head[ro + lane + 64];
            const float mp = s_mask[p];

            // true IEEE division by 30.0f: matches numpy floor(x/30) at bin edges
            int i1 = (int)floorf(hq0 / 30.0f); i1 = i1 < 0 ? 0 : (i1 > 11 ? 11 : i1);
            int i2 = (int)floorf(bq0 / 30.0f); i2 = i2 < 0 ? 0 : (i2 > 11 ? 11 : i2);
            float wv0 = s_dom[i1 * 12 + i2] - dq0;
            bool on0 = (wv0 > 0.0f) && (mp != 0.0f) && (mq0 != 0.0f) && (lane != p);
            float e0 = on0 ? (expf(wv0) + EPSF) : EPSF;

            int k1 = (int)floorf(hq1 / 30.0f); k1 = k1 < 0 ? 0 : (k1 > 11 ? 11 : k1);
            int k2 = (int)floorf(bq1 / 30.0f); k2 = k2 < 0 ? 0 : (k2 > 11 ? 11 : k2);
            float wv1 = s_dom[k1 * 12 + k2] - dq1;
            bool on1 = (wv1 > 0.0f) && (mp != 0.0f) && (mq1 != 0.0f) && ((lane + 64) != p);
            float e1 = on1 ? (expf(wv1) + EPSF) : EPSF;

            // consecutive-lane bf16 writes: 2-way bank aliasing (free)
            s_w[p * SW + lane]      = f2bf(e0);
            s_w[p * SW + lane + 64] = f2bf(e1);
        }
    }

    // ---- phase 2: wh_unnorm = E @ h + row sums via ones-MFMA (K=128) ----
    // A[m=l16][k=quad*8+j] from own rows; B[k][n=l16] from s_hT[n][k].
    f32x4 acc[4], accs;
    #pragma unroll
    for (int tj = 0; tj < 4; ++tj) acc[tj] = (f32x4){0.f, 0.f, 0.f, 0.f};
    accs = (f32x4){0.f, 0.f, 0.f, 0.f};

    short8 ones;
    #pragma unroll
    for (int i = 0; i < 8; ++i) ones[i] = (short)0x3F80;  // bf16 1.0

    #pragma unroll
    for (int kb = 0; kb < 4; ++kb) {
        const int ko = kb * 32 + quad * 8;
        short8 a = *(const short8*)&s_w[(R0 + l16) * SW + ko];
        accs = __builtin_amdgcn_mfma_f32_16x16x32_bf16(a, ones, accs, 0, 0, 0);
        #pragma unroll
        for (int tj = 0; tj < 4; ++tj) {
            short8 bf = *(const short8*)&s_hT[(tj * 16 + l16) * SW + ko];
            acc[tj] = __builtin_amdgcn_mfma_f32_16x16x32_bf16(a, bf, acc[tj], 0, 0, 0);
        }
    }

    // C/D row = quad*4 + r matches accs rows lane-for-lane.
    float inv[4];
    #pragma unroll
    for (int r = 0; r < 4; ++r) inv[r] = 1.0f / (accs[r] + EPSF);

    // ---- build fused rows [wh | h] in s_w (wave-local; DS is in-order) ----
    #pragma unroll
    for (int tj = 0; tj < 4; ++tj)
        #pragma unroll
        for (int r = 0; r < 4; ++r) {
            int row = R0 + quad * 4 + r;
            s_w[row * SW + tj * 16 + l16] = f2bf(acc[tj][r] * inv[r]);
        }
    {
        const float* hb = hidden + (size_t)b * NP * ND;
        #pragma unroll 4
        for (int i = 0; i < 16; ++i) {      // L2-warm coalesced re-read of own rows
            float hv = hb[(size_t)(R0 + i) * ND + lane];
            s_w[(R0 + i) * SW + 64 + lane] = f2bf(hv);
        }
    }

    // ---- phase 3: out = tanh(fused @ W^T + b) via MFMA (K=128) ----
    f32x4 acc2[4];
    #pragma unroll
    for (int tj = 0; tj < 4; ++tj) acc2[tj] = (f32x4){0.f, 0.f, 0.f, 0.f};

    #pragma unroll
    for (int kb = 0; kb < 4; ++kb) {
        const int ko = kb * 32 + quad * 8;
        short8 a = *(const short8*)&s_w[(R0 + l16) * SW + ko];
        #pragma unroll
        for (int tj = 0; tj < 4; ++tj) {
            short8 bf = *(const short8*)&s_Wm[(tj * 16 + l16) * SW + ko];
            acc2[tj] = __builtin_amdgcn_mfma_f32_16x16x32_bf16(a, bf, acc2[tj], 0, 0, 0);
        }
    }

    float bvals[4];
    #pragma unroll
    for (int tj = 0; tj < 4; ++tj) bvals[tj] = bias[tj * 16 + l16];

    float* ob = out + (size_t)b * NP * ND;
    #pragma unroll
    for (int tj = 0; tj < 4; ++tj)
        #pragma unroll
        for (int r = 0; r < 4; ++r) {
            int row = R0 + quad * 4 + r;
            ob[(size_t)row * ND + tj * 16 + l16] = tanhf(acc2[tj][r] + bvals[tj]);
        }
}

extern "C" void kernel_launch(void* const* d_in, const int* in_sizes, int n_in,
                              void* d_out, int out_size, void* d_ws, size_t ws_size,
                              hipStream_t stream) {
    const float* hidden = (const float*)d_in[0];
    const float* dist   = (const float*)d_in[1];
    const float* bear   = (const float*)d_in[2];
    const float* head   = (const float*)d_in[3];
    const float* smask  = (const float*)d_in[4];
    const float* domain = (const float*)d_in[5];
    const float* W      = (const float*)d_in[6];
    const float* bias   = (const float*)d_in[7];
    float* out = (float*)d_out;

    spatial_attn_kernel<<<dim3(NB), dim3(512), 0, stream>>>(
        hidden, dist, bear, head, smask, domain, W, bias, out);
}